// Round 12
// baseline (443.434 us; speedup 1.0000x reference)
//
#include <hip/hip_runtime.h>
#include <hip/hip_bf16.h>

#define T_ 256
#define B_ 16
#define S_ 64
#define D_ 256

typedef __attribute__((ext_vector_type(4))) int int4v;

// LDS-visibility-only barrier: waits DS ops, leaves global loads/stores/atomics
// in flight across the barrier (avoids the __syncthreads vmcnt(0) drain).
#define LDS_BARRIER() asm volatile("s_waitcnt lgkmcnt(0)\n\ts_barrier" ::: "memory")

// ---------------- W_x transpose: WxT[k][d] = W_x[d][k] ----------------
__global__ void k_transpose(const float* __restrict__ in, float* __restrict__ out) {
    __shared__ float tile[32][33];
    int tx = threadIdx.x & 31, ty = threadIdx.x >> 5;
    int bx = blockIdx.x & 7, by = blockIdx.x >> 3;
    tile[ty][tx] = in[(by * 32 + ty) * D_ + bx * 32 + tx];
    __syncthreads();
    out[(bx * 32 + ty) * D_ + by * 32 + tx] = tile[tx][ty];
}

// ---- wz[t*B+b][d] = { bias[d] + sum_k x[t,b,k]*WxT[k][d],  silu(z[t,b,d]) } ----
__global__ __launch_bounds__(256) void k_wxall(const float* __restrict__ x,
                                               const float* __restrict__ z,
                                               const float* __restrict__ WxT,
                                               const float* __restrict__ bias,
                                               float2* __restrict__ wz) {
    __shared__ float xs[16][D_];
    const int tid = threadIdx.x;
    const int row0 = blockIdx.x * 16;
    for (int r = 0; r < 16; ++r)
        xs[r][tid] = x[(size_t)(row0 + r) * D_ + tid];
    __syncthreads();
    float acc[16];
    float bv = bias[tid];
#pragma unroll
    for (int r = 0; r < 16; ++r) acc[r] = bv;
    for (int k = 0; k < D_; ++k) {
        float wv = WxT[k * D_ + tid];
#pragma unroll
        for (int r = 0; r < 16; ++r) acc[r] = __builtin_fmaf(wv, xs[r][k], acc[r]);
    }
    for (int r = 0; r < 16; ++r) {
        float zv = z[(size_t)(row0 + r) * D_ + tid];
        float sil = zv * __builtin_amdgcn_rcpf(1.0f + __expf(-zv));
        wz[(size_t)(row0 + r) * D_ + tid] = make_float2(acc[r], sil);
    }
}

// ------------- main recurrence: TWO interleaved problem-groups / block -------------
// grid = 128 blocks: block -> b = blk>>3, s0 = (blk&7)*8; problem A = slots
// s0..s0+3, problem B = slots s0+4..s0+7 (same b => shared wz + shared output
// atomic address). block = 512 threads = 8 waves (2/SIMD); wave w owns n-slice
// [32w, 32w+32) for BOTH problems. One barrier advances both problems one step:
// B's reads/MFMA/tail fill A's latency windows (barrier+ds_read+mfma-dep+exp),
// amortizing the serial-chain cost over 2 steps. Wh B-fragments are shared.
__global__ __launch_bounds__(512, 1) void k_rec(
    const float* __restrict__ Wh,      // [D][D] (n-major: Wh[n][k])
    const float2* __restrict__ wz,     // [T*B][D] {wx+bias, silu(z)}
    const float* __restrict__ h0,      // [B][S][D]
    const float* __restrict__ Cvec,    // [S]
    float* __restrict__ outputs,       // [T*B][D], pre-zeroed (atomic accum)
    float* __restrict__ h_out)         // [(T+1)*B][S][D]
{
    const int tid  = threadIdx.x;
    const int w    = tid >> 6;
    const int lane = tid & 63;
    const int l16  = lane & 15;
    const int quad = lane >> 4;
    const int b    = blockIdx.x >> 3;
    const int s0   = (blockIdx.x & 7) * 8;     // 8 slots: A = s0..s0+3, B = s0+4..s0+7
    const int r0   = quad & 2;                 // slot-pair this thread finalizes
    const int d    = (w << 5) | (lane & 31);   // this thread's output column

    // ping-pong h buffers, i8, per problem. Row stride 288 B: b128 A-chunks
    // land 2-way per bank (free, m136); b8 writes showed 0 conflicts R3-R11.
    __shared__ __align__(16) signed char hA8[2][2][4][288];   // [pp][prob][row][d]

    // init from h0 and write h[0] = h0  (8 slots x 256 d, 512 threads, 4 iters)
    for (int i = tid; i < 8 * D_; i += 512) {
        int r = i >> 8, dd = i & 255;          // r = 0..7
        float v = h0[(size_t)(b * S_ + s0 + r) * D_ + dd];
        float vc = fminf(fmaxf(v, -1.0f), 1.0f);
        hA8[0][r >> 2][r & 3][dd] = (signed char)__float2int_rn(vc * 127.0f);
        h_out[(size_t)(b * S_ + s0 + r) * D_ + dd] = v;
    }

    // ---- pass 1: per-column absmax of Wh for cols n = 32w + nt*16 + l16 ----
    float cmax[2];
#pragma unroll
    for (int nt = 0; nt < 2; ++nt) {
        const float* wr = Wh + (size_t)(w * 32 + nt * 16 + l16) * D_ + quad * 16;
        float cm = 1e-20f;
#pragma unroll
        for (int kt = 0; kt < 4; ++kt) {
            const float* p = wr + kt * 64;
#pragma unroll
            for (int j = 0; j < 16; j += 4) {
                float4 v = *(const float4*)(p + j);
                cm = fmaxf(cm, fmaxf(fmaxf(fabsf(v.x), fabsf(v.y)),
                                     fmaxf(fabsf(v.z), fabsf(v.w))));
            }
        }
        cm = fmaxf(cm, __shfl_xor(cm, 16, 64));
        cm = fmaxf(cm, __shfl_xor(cm, 32, 64));
        cmax[nt] = cm;
    }

    // ---- pass 2: quantize Wh -> i8 B-fragments (32 VGPRs, SHARED by A and B) ----
    int4v Bf[4][2];
#pragma unroll
    for (int nt = 0; nt < 2; ++nt) {
        const float rs = 127.0f / cmax[nt];
        const float* wr = Wh + (size_t)(w * 32 + nt * 16 + l16) * D_ + quad * 16;
#pragma unroll
        for (int kt = 0; kt < 4; ++kt) {
            const float* p = wr + kt * 64;
            int4v frag;
#pragma unroll
            for (int r = 0; r < 4; ++r) {
                float4 v = *(const float4*)(p + r * 4);
                int q0 = __float2int_rn(v.x * rs) & 255;
                int q1 = __float2int_rn(v.y * rs) & 255;
                int q2 = __float2int_rn(v.z * rs) & 255;
                int q3 = __float2int_rn(v.w * rs) & 255;
                frag[r] = q0 | (q1 << 8) | (q2 << 16) | (q3 << 24);
            }
            Bf[kt][nt] = frag;
        }
    }
    // dequant scale folded with the tanh x2: pre2 = 2*(acc*dscale + wx)
    const float dscale2 = ((quad & 1) ? cmax[1] : cmax[0]) * (2.0f / 16129.0f);
    // C coefficients pre-scaled by 1/127 (deferred values are 127*h)
    const float cA0 = Cvec[s0 + r0]     * (1.0f / 127.0f);
    const float cA1 = Cvec[s0 + r0 + 1] * (1.0f / 127.0f);
    const float cB0 = Cvec[s0 + 4 + r0]     * (1.0f / 127.0f);
    const float cB1 = Cvec[s0 + 4 + r0 + 1] * (1.0f / 127.0f);

    // prologue: wz for t=0 and t=1 (shared by A and B); running pointers
    const float2* wzp = wz + (size_t)b * D_ + d;
    float2 wzr[2];
    wzr[0] = wzp[0];
    wzr[1] = wzp[(size_t)B_ * D_];
    wzp += (size_t)2 * B_ * D_;                 // points at t=2's row

    // deferred output state of step t-1 (127*tanh values, both problems)
    float f0A = 0.f, f1A = 0.f, f0B = 0.f, f1B = 0.f, fsil = 0.f;
    float* hpA = h_out + (size_t)(1 * B_ + b) * (S_ * D_) + (size_t)(s0 + r0) * D_ + d;
    float* hpB = hpA + (size_t)4 * D_;
    float* op  = outputs + (size_t)b * D_ + d;

    __syncthreads();   // full barrier once (init visibility incl. global)

// PF = 1: prefetch wz for t+2 (main body); PF = 0: last two steps, no prefetch.
#define STEP(t, CUR, NXT, PF)                                                  \
    {                                                                          \
        const signed char* apA = &hA8[CUR][0][l16 & 3][quad * 16];             \
        const signed char* apB = &hA8[CUR][1][l16 & 3][quad * 16];             \
        int4v AfA0 = *(const int4v*)(apA);                                     \
        int4v AfB0 = *(const int4v*)(apB);                                     \
        int4v AfA1 = *(const int4v*)(apA + 64);                                \
        int4v AfB1 = *(const int4v*)(apB + 64);                                \
        int4v AfA2 = *(const int4v*)(apA + 128);                               \
        int4v AfB2 = *(const int4v*)(apB + 128);                               \
        int4v AfA3 = *(const int4v*)(apA + 192);                               \
        int4v AfB3 = *(const int4v*)(apB + 192);                               \
        if ((t) >= 1) { /* step t-1's output path, in the ds_read shadow */    \
            __builtin_nontemporal_store(f0A * (1.0f / 127.0f), hpA);           \
            __builtin_nontemporal_store(f1A * (1.0f / 127.0f), hpA + D_);      \
            __builtin_nontemporal_store(f0B * (1.0f / 127.0f), hpB);           \
            __builtin_nontemporal_store(f1B * (1.0f / 127.0f), hpB + D_);      \
            hpA += B_ * S_ * D_; hpB += B_ * S_ * D_;                          \
            float part = __builtin_fmaf(cA0, f0A, cA1 * f1A)                   \
                       + __builtin_fmaf(cB0, f0B, cB1 * f1B);                  \
            part += __shfl_xor(part, 32, 64);  /* combine slot-pairs */        \
            if (quad < 2) atomicAdd(op, part * fsil);                          \
            op += B_ * D_;                                                     \
        }                                                                      \
        float wx2 = wzr[CUR].x + wzr[CUR].x;                                   \
        fsil      = wzr[CUR].y;                                                \
        if (PF) { wzr[CUR] = *wzp; wzp += (size_t)B_ * D_; }                   \
        /* 8 independent 2-deep MFMA chains, A/B interleaved (dep dist 8) */   \
        int4v aA0a = {0,0,0,0}, aA0b = aA0a, aA1a = aA0a, aA1b = aA0a;         \
        int4v aB0a = aA0a, aB0b = aA0a, aB1a = aA0a, aB1b = aA0a;              \
        aA0a = __builtin_amdgcn_mfma_i32_16x16x64_i8(AfA0, Bf[0][0], aA0a, 0, 0, 0); \
        aB0a = __builtin_amdgcn_mfma_i32_16x16x64_i8(AfB0, Bf[0][0], aB0a, 0, 0, 0); \
        aA1a = __builtin_amdgcn_mfma_i32_16x16x64_i8(AfA0, Bf[0][1], aA1a, 0, 0, 0); \
        aB1a = __builtin_amdgcn_mfma_i32_16x16x64_i8(AfB0, Bf[0][1], aB1a, 0, 0, 0); \
        aA0b = __builtin_amdgcn_mfma_i32_16x16x64_i8(AfA1, Bf[1][0], aA0b, 0, 0, 0); \
        aB0b = __builtin_amdgcn_mfma_i32_16x16x64_i8(AfB1, Bf[1][0], aB0b, 0, 0, 0); \
        aA1b = __builtin_amdgcn_mfma_i32_16x16x64_i8(AfA1, Bf[1][1], aA1b, 0, 0, 0); \
        aB1b = __builtin_amdgcn_mfma_i32_16x16x64_i8(AfB1, Bf[1][1], aB1b, 0, 0, 0); \
        aA0a = __builtin_amdgcn_mfma_i32_16x16x64_i8(AfA2, Bf[2][0], aA0a, 0, 0, 0); \
        aB0a = __builtin_amdgcn_mfma_i32_16x16x64_i8(AfB2, Bf[2][0], aB0a, 0, 0, 0); \
        aA1a = __builtin_amdgcn_mfma_i32_16x16x64_i8(AfA2, Bf[2][1], aA1a, 0, 0, 0); \
        aB1a = __builtin_amdgcn_mfma_i32_16x16x64_i8(AfB2, Bf[2][1], aB1a, 0, 0, 0); \
        aA0b = __builtin_amdgcn_mfma_i32_16x16x64_i8(AfA3, Bf[3][0], aA0b, 0, 0, 0); \
        aB0b = __builtin_amdgcn_mfma_i32_16x16x64_i8(AfB3, Bf[3][0], aB0b, 0, 0, 0); \
        aA1b = __builtin_amdgcn_mfma_i32_16x16x64_i8(AfA3, Bf[3][1], aA1b, 0, 0, 0); \
        aB1b = __builtin_amdgcn_mfma_i32_16x16x64_i8(AfB3, Bf[3][1], aB1b, 0, 0, 0); \
        /* problem A epilogue */                                               \
        {                                                                      \
            int u0 = (quad & 2) ? aA0a[2] : aA0a[0];                           \
            int u1 = (quad & 2) ? aA0b[2] : aA0b[0];                           \
            int v0 = (quad & 2) ? aA1a[2] : aA1a[0];                           \
            int v1 = (quad & 2) ? aA1b[2] : aA1b[0];                           \
            int sa = (quad & 1) ? (v0 + v1) : (u0 + u1);                       \
            int u2 = (quad & 2) ? aA0a[3] : aA0a[1];                           \
            int u3 = (quad & 2) ? aA0b[3] : aA0b[1];                           \
            int v2 = (quad & 2) ? aA1a[3] : aA1a[1];                           \
            int v3 = (quad & 2) ? aA1b[3] : aA1b[1];                           \
            int sb = (quad & 1) ? (v2 + v3) : (u2 + u3);                       \
            float e0 = __expf(__builtin_fmaf((float)sa, dscale2, wx2));        \
            float e1 = __expf(__builtin_fmaf((float)sb, dscale2, wx2));        \
            float g0 = __builtin_fmaf(-254.0f, __builtin_amdgcn_rcpf(e0 + 1.0f), 127.0f); \
            float g1 = __builtin_fmaf(-254.0f, __builtin_amdgcn_rcpf(e1 + 1.0f), 127.0f); \
            hA8[NXT][0][r0][d]     = (signed char)__float2int_rn(g0);          \
            hA8[NXT][0][r0 + 1][d] = (signed char)__float2int_rn(g1);          \
            f0A = g0; f1A = g1;                                                \
        }                                                                      \
        /* problem B epilogue */                                               \
        {                                                                      \
            int u0 = (quad & 2) ? aB0a[2] : aB0a[0];                           \
            int u1 = (quad & 2) ? aB0b[2] : aB0b[0];                           \
            int v0 = (quad & 2) ? aB1a[2] : aB1a[0];                           \
            int v1 = (quad & 2) ? aB1b[2] : aB1b[0];                           \
            int sa = (quad & 1) ? (v0 + v1) : (u0 + u1);                       \
            int u2 = (quad & 2) ? aB0a[3] : aB0a[1];                           \
            int u3 = (quad & 2) ? aB0b[3] : aB0b[1];                           \
            int v2 = (quad & 2) ? aB1a[3] : aB1a[1];                           \
            int v3 = (quad & 2) ? aB1b[3] : aB1b[1];                           \
            int sb = (quad & 1) ? (v2 + v3) : (u2 + u3);                       \
            float e0 = __expf(__builtin_fmaf((float)sa, dscale2, wx2));        \
            float e1 = __expf(__builtin_fmaf((float)sb, dscale2, wx2));        \
            float g0 = __builtin_fmaf(-254.0f, __builtin_amdgcn_rcpf(e0 + 1.0f), 127.0f); \
            float g1 = __builtin_fmaf(-254.0f, __builtin_amdgcn_rcpf(e1 + 1.0f), 127.0f); \
            hA8[NXT][1][r0][d]     = (signed char)__float2int_rn(g0);          \
            hA8[NXT][1][r0 + 1][d] = (signed char)__float2int_rn(g1);          \
            f0B = g0; f1B = g1;                                                \
        }                                                                      \
        LDS_BARRIER();                                                         \
    }

    for (int t2 = 0; t2 < T_ - 2; t2 += 2) {
        STEP(t2, 0, 1, 1)
        STEP(t2 + 1, 1, 0, 1)
    }
    STEP(T_ - 2, 0, 1, 0)
    STEP(T_ - 1, 1, 0, 0)
#undef STEP

    // tail: flush step T-1's output path
    {
        __builtin_nontemporal_store(f0A * (1.0f / 127.0f), hpA);
        __builtin_nontemporal_store(f1A * (1.0f / 127.0f), hpA + D_);
        __builtin_nontemporal_store(f0B * (1.0f / 127.0f), hpB);
        __builtin_nontemporal_store(f1B * (1.0f / 127.0f), hpB + D_);
        float part = __builtin_fmaf(cA0, f0A, cA1 * f1A)
                   + __builtin_fmaf(cB0, f0B, cB1 * f1B);
        part += __shfl_xor(part, 32, 64);
        if (quad < 2) atomicAdd(op, part * fsil);
    }
}

extern "C" void kernel_launch(void* const* d_in, const int* in_sizes, int n_in,
                              void* d_out, int out_size, void* d_ws, size_t ws_size,
                              hipStream_t stream) {
    const float* x    = (const float*)d_in[0];
    const float* z    = (const float*)d_in[1];
    const float* h0   = (const float*)d_in[2];
    const float* W_x  = (const float*)d_in[3];
    const float* W_h  = (const float*)d_in[4];
    const float* bias = (const float*)d_in[5];
    const float* C    = (const float*)d_in[6];

    float* outputs = (float*)d_out;                     // [T*B*D]
    float* h_out   = outputs + (size_t)T_ * B_ * D_;    // [(T+1)*B*S*D]

    float*  WxT = (float*)d_ws;                         // D*D floats
    float2* wz  = (float2*)(WxT + D_ * D_);             // T*B*D float2

    hipMemsetAsync(outputs, 0, (size_t)T_ * B_ * D_ * sizeof(float), stream);
    k_transpose<<<64, 1024, 0, stream>>>(W_x, WxT);
    k_wxall<<<T_ * B_ / 16, 256, 0, stream>>>(x, z, WxT, bias, wz);
    k_rec<<<B_ * S_ / 8, 512, 0, stream>>>(W_h, wz, h0, C, outputs, h_out);
}

// Round 13
// 377.879 us; speedup vs baseline: 1.1735x; 1.1735x over previous
//
#include <hip/hip_runtime.h>
#include <hip/hip_bf16.h>

#define T_ 256
#define B_ 16
#define S_ 64
#define D_ 256

typedef __attribute__((ext_vector_type(4))) int int4v;

// LDS-visibility-only barrier: waits DS ops, leaves global loads/stores/atomics
// in flight across the barrier (avoids the __syncthreads vmcnt(0) drain).
#define LDS_BARRIER() asm volatile("s_waitcnt lgkmcnt(0)\n\ts_barrier" ::: "memory")

// ---------------- W_x transpose: WxT[k][d] = W_x[d][k] ----------------
__global__ void k_transpose(const float* __restrict__ in, float* __restrict__ out) {
    __shared__ float tile[32][33];
    int tx = threadIdx.x & 31, ty = threadIdx.x >> 5;
    int bx = blockIdx.x & 7, by = blockIdx.x >> 3;
    tile[ty][tx] = in[(by * 32 + ty) * D_ + bx * 32 + tx];
    __syncthreads();
    out[(bx * 32 + ty) * D_ + by * 32 + tx] = tile[tx][ty];
}

// ---- wz[t*B+b][d] = { bias[d] + sum_k x[t,b,k]*WxT[k][d],  silu(z[t,b,d]) } ----
__global__ __launch_bounds__(256) void k_wxall(const float* __restrict__ x,
                                               const float* __restrict__ z,
                                               const float* __restrict__ WxT,
                                               const float* __restrict__ bias,
                                               float2* __restrict__ wz) {
    __shared__ float xs[16][D_];
    const int tid = threadIdx.x;
    const int row0 = blockIdx.x * 16;
    for (int r = 0; r < 16; ++r)
        xs[r][tid] = x[(size_t)(row0 + r) * D_ + tid];
    __syncthreads();
    float acc[16];
    float bv = bias[tid];
#pragma unroll
    for (int r = 0; r < 16; ++r) acc[r] = bv;
    for (int k = 0; k < D_; ++k) {
        float wv = WxT[k * D_ + tid];
#pragma unroll
        for (int r = 0; r < 16; ++r) acc[r] = __builtin_fmaf(wv, xs[r][k], acc[r]);
    }
    for (int r = 0; r < 16; ++r) {
        float zv = z[(size_t)(row0 + r) * D_ + tid];
        float sil = zv * __builtin_amdgcn_rcpf(1.0f + __expf(-zv));
        wz[(size_t)(row0 + r) * D_ + tid] = make_float2(acc[r], sil);
    }
}

// ---------------- main recurrence (i8 MFMA K=64, 4 slots, 8 waves) ----------------
// grid = 256 blocks: block -> (b = blk>>4, slots s0..s0+3, s0 = (blk&15)*4)
// block = 512 threads = 8 waves (2/SIMD — best measured across {4,8,16} waves,
// {2,4} slots/block, {1,2} problems/block; see R5/R6/R10/R12 post-mortems).
// Step wall ~1210 cyc = LDS burst + MFMA issue (326/SIMD, M-pack invariant) +
// epilogue VALU + barrier/ds latency; all terms mandatory for this topology.
// Pre-barrier tail minimized: LDS byte = 127*tanh(pre) via
// 127 - 254/(exp(2*pre)+1) (x2 folded into dscale2/wx2), i8 rounding via the
// +1.5*2^23 magic-number trick (RNE-identical, saves rndne+cvt on the tail).
// ALL float post-processing (h/127, C-partial, silu) deferred to the next
// step's ds_read latency shadow.
__global__ __launch_bounds__(512, 1) void k_rec(
    const float* __restrict__ Wh,      // [D][D] (n-major: Wh[n][k])
    const float2* __restrict__ wz,     // [T*B][D] {wx+bias, silu(z)}
    const float* __restrict__ h0,      // [B][S][D]
    const float* __restrict__ Cvec,    // [S]
    float* __restrict__ outputs,       // [T*B][D], pre-zeroed (atomic accum)
    float* __restrict__ h_out)         // [(T+1)*B][S][D]
{
    const int tid  = threadIdx.x;
    const int w    = tid >> 6;
    const int lane = tid & 63;
    const int l16  = lane & 15;
    const int quad = lane >> 4;
    const int b    = blockIdx.x >> 4;
    const int s0   = (blockIdx.x & 15) * 4;
    const int r0   = quad & 2;                 // slot-pair this thread finalizes
    const int d    = (w << 5) | (lane & 31);   // this thread's output column

    // ping-pong h buffer, i8. Row stride 288 B: the 16 distinct b128 A-chunks
    // land 2-way per bank (free, m136); b8 writes showed 0 conflicts R3-R12.
    __shared__ __align__(16) signed char hA8[2][4][288];

    // init hA8[0] from h0 and write h[0] = h0  (512 threads, 2 iters)
    for (int i = tid; i < 4 * D_; i += 512) {
        int r = i >> 8, dd = i & 255;
        float v = h0[(size_t)(b * S_ + s0 + r) * D_ + dd];
        float vc = fminf(fmaxf(v, -1.0f), 1.0f);
        hA8[0][r][dd] = (signed char)__float2int_rn(vc * 127.0f);
        h_out[(size_t)(b * S_ + s0 + r) * D_ + dd] = v;
    }

    // ---- pass 1: per-column absmax of Wh for cols n = 32w + nt*16 + l16 ----
    float cmax[2];
#pragma unroll
    for (int nt = 0; nt < 2; ++nt) {
        const float* wr = Wh + (size_t)(w * 32 + nt * 16 + l16) * D_ + quad * 16;
        float cm = 1e-20f;
#pragma unroll
        for (int kt = 0; kt < 4; ++kt) {
            const float* p = wr + kt * 64;
#pragma unroll
            for (int j = 0; j < 16; j += 4) {
                float4 v = *(const float4*)(p + j);
                cm = fmaxf(cm, fmaxf(fmaxf(fabsf(v.x), fabsf(v.y)),
                                     fmaxf(fabsf(v.z), fabsf(v.w))));
            }
        }
        cm = fmaxf(cm, __shfl_xor(cm, 16, 64));
        cm = fmaxf(cm, __shfl_xor(cm, 32, 64));
        cmax[nt] = cm;
    }

    // ---- pass 2: quantize Wh -> i8 B-fragments (32 VGPRs) ----
    // lane holds B[k = kt*64 + quad*16 + j][n = 32w + nt*16 + l16]
    int4v Bf[4][2];
#pragma unroll
    for (int nt = 0; nt < 2; ++nt) {
        const float rs = 127.0f / cmax[nt];
        const float* wr = Wh + (size_t)(w * 32 + nt * 16 + l16) * D_ + quad * 16;
#pragma unroll
        for (int kt = 0; kt < 4; ++kt) {
            const float* p = wr + kt * 64;
            int4v frag;
#pragma unroll
            for (int r = 0; r < 4; ++r) {
                float4 v = *(const float4*)(p + r * 4);
                int q0 = __float2int_rn(v.x * rs) & 255;
                int q1 = __float2int_rn(v.y * rs) & 255;
                int q2 = __float2int_rn(v.z * rs) & 255;
                int q3 = __float2int_rn(v.w * rs) & 255;
                frag[r] = q0 | (q1 << 8) | (q2 << 16) | (q3 << 24);
            }
            Bf[kt][nt] = frag;
        }
    }
    // dequant scale folded with the tanh x2: pre2 = 2*(acc*dscale + wx)
    const float dscale2 = ((quad & 1) ? cmax[1] : cmax[0]) * (2.0f / 16129.0f);
    // C coefficients pre-scaled by 1/127 (deferred values are 127*h)
    const float c0i = Cvec[s0 + r0] * (1.0f / 127.0f);
    const float c1i = Cvec[s0 + r0 + 1] * (1.0f / 127.0f);

    // prologue: wz for t=0 and t=1; running pointers
    const float2* wzp = wz + (size_t)b * D_ + d;
    float2 wzr[2];
    wzr[0] = wzp[0];
    wzr[1] = wzp[(size_t)B_ * D_];
    wzp += (size_t)2 * B_ * D_;                 // points at t=2's row

    // deferred output state of step t-1: f0/f1 hold 127*tanh values
    float f0 = 0.f, f1 = 0.f, fsil = 0.f;
    float* hp = h_out + (size_t)(1 * B_ + b) * (S_ * D_) + (size_t)s0 * D_ + (size_t)r0 * D_ + d;
    float* op = outputs + (size_t)b * D_ + d;

    __syncthreads();   // full barrier once (init visibility incl. global)

// PF = 1: prefetch wz for t+2 (main body); PF = 0: last two steps, no prefetch.
#define STEP(t, CUR, NXT, PF)                                                  \
    {                                                                          \
        const signed char* ap = &hA8[CUR][l16 & 3][quad * 16];                 \
        int4v Af0 = *(const int4v*)(ap);                                       \
        int4v Af1 = *(const int4v*)(ap + 64);                                  \
        int4v Af2 = *(const int4v*)(ap + 128);                                 \
        int4v Af3 = *(const int4v*)(ap + 192);                                 \
        if ((t) >= 1) { /* step t-1's output path, in the ds_read shadow */    \
            float hv0 = f0 * (1.0f / 127.0f);                                  \
            float hv1 = f1 * (1.0f / 127.0f);                                  \
            __builtin_nontemporal_store(hv0, hp);                              \
            __builtin_nontemporal_store(hv1, hp + D_);                         \
            hp += B_ * S_ * D_;                                                \
            float part = __builtin_fmaf(c0i, f0, c1i * f1);                    \
            part += __shfl_xor(part, 32, 64);  /* combine slot-pairs */        \
            if (quad < 2) atomicAdd(op, part * fsil);                          \
            op += B_ * D_;                                                     \
        }                                                                      \
        float wx2 = wzr[CUR].x + wzr[CUR].x;                                   \
        fsil      = wzr[CUR].y;                                                \
        if (PF) { wzr[CUR] = *wzp; wzp += (size_t)B_ * D_; }                   \
        /* 4 independent 2-deep MFMA chains; dep pairs 4 instrs apart */       \
        int4v a0a = {0, 0, 0, 0}, a0b = a0a, a1a = a0a, a1b = a0a;             \
        a0a = __builtin_amdgcn_mfma_i32_16x16x64_i8(Af0, Bf[0][0], a0a, 0, 0, 0); \
        a1a = __builtin_amdgcn_mfma_i32_16x16x64_i8(Af0, Bf[0][1], a1a, 0, 0, 0); \
        a0b = __builtin_amdgcn_mfma_i32_16x16x64_i8(Af1, Bf[1][0], a0b, 0, 0, 0); \
        a1b = __builtin_amdgcn_mfma_i32_16x16x64_i8(Af1, Bf[1][1], a1b, 0, 0, 0); \
        a0a = __builtin_amdgcn_mfma_i32_16x16x64_i8(Af2, Bf[2][0], a0a, 0, 0, 0); \
        a1a = __builtin_amdgcn_mfma_i32_16x16x64_i8(Af2, Bf[2][1], a1a, 0, 0, 0); \
        a0b = __builtin_amdgcn_mfma_i32_16x16x64_i8(Af3, Bf[3][0], a0b, 0, 0, 0); \
        a1b = __builtin_amdgcn_mfma_i32_16x16x64_i8(Af3, Bf[3][1], a1b, 0, 0, 0); \
        /* select per chain (C rows quad-replicated), then add chain halves */ \
        int u0 = (quad & 2) ? a0a[2] : a0a[0];                                 \
        int u1 = (quad & 2) ? a0b[2] : a0b[0];                                 \
        int v0 = (quad & 2) ? a1a[2] : a1a[0];                                 \
        int v1 = (quad & 2) ? a1b[2] : a1b[0];                                 \
        int sa = (quad & 1) ? (v0 + v1) : (u0 + u1);                           \
        int u2 = (quad & 2) ? a0a[3] : a0a[1];                                 \
        int u3 = (quad & 2) ? a0b[3] : a0b[1];                                 \
        int v2 = (quad & 2) ? a1a[3] : a1a[1];                                 \
        int v3 = (quad & 2) ? a1b[3] : a1b[1];                                 \
        int sb = (quad & 1) ? (v2 + v3) : (u2 + u3);                           \
        /* 127*tanh(pre) = 127 - 254/(exp(2*pre)+1); minimal chain to LDS */   \
        float e0 = __expf(__builtin_fmaf((float)sa, dscale2, wx2));            \
        float e1 = __expf(__builtin_fmaf((float)sb, dscale2, wx2));            \
        float g0 = __builtin_fmaf(-254.0f, __builtin_amdgcn_rcpf(e0 + 1.0f), 127.0f); \
        float g1 = __builtin_fmaf(-254.0f, __builtin_amdgcn_rcpf(e1 + 1.0f), 127.0f); \
        /* i8 RNE via magic number: low byte of bits(g + 1.5*2^23) */          \
        union { float f; int i; } m0, m1;                                      \
        m0.f = g0 + 12582912.0f;                                               \
        m1.f = g1 + 12582912.0f;                                               \
        hA8[NXT][r0][d]     = (signed char)m0.i;                               \
        hA8[NXT][r0 + 1][d] = (signed char)m1.i;                               \
        f0 = g0; f1 = g1;                                                      \
        LDS_BARRIER();                                                         \
    }

    for (int t2 = 0; t2 < T_ - 2; t2 += 2) {
        STEP(t2, 0, 1, 1)
        STEP(t2 + 1, 1, 0, 1)
    }
    STEP(T_ - 2, 0, 1, 0)
    STEP(T_ - 1, 1, 0, 0)
#undef STEP

    // tail: flush step T-1's output path
    {
        float hv0 = f0 * (1.0f / 127.0f);
        float hv1 = f1 * (1.0f / 127.0f);
        __builtin_nontemporal_store(hv0, hp);
        __builtin_nontemporal_store(hv1, hp + D_);
        float part = __builtin_fmaf(c0i, f0, c1i * f1);
        part += __shfl_xor(part, 32, 64);
        if (quad < 2) atomicAdd(op, part * fsil);
    }
}

extern "C" void kernel_launch(void* const* d_in, const int* in_sizes, int n_in,
                              void* d_out, int out_size, void* d_ws, size_t ws_size,
                              hipStream_t stream) {
    const float* x    = (const float*)d_in[0];
    const float* z    = (const float*)d_in[1];
    const float* h0   = (const float*)d_in[2];
    const float* W_x  = (const float*)d_in[3];
    const float* W_h  = (const float*)d_in[4];
    const float* bias = (const float*)d_in[5];
    const float* C    = (const float*)d_in[6];

    float* outputs = (float*)d_out;                     // [T*B*D]
    float* h_out   = outputs + (size_t)T_ * B_ * D_;    // [(T+1)*B*S*D]

    float*  WxT = (float*)d_ws;                         // D*D floats
    float2* wz  = (float2*)(WxT + D_ * D_);             // T*B*D float2

    hipMemsetAsync(outputs, 0, (size_t)T_ * B_ * D_ * sizeof(float), stream);
    k_transpose<<<64, 1024, 0, stream>>>(W_x, WxT);
    k_wxall<<<T_ * B_ / 16, 256, 0, stream>>>(x, z, WxT, bias, wz);
    k_rec<<<B_ * S_ / 4, 512, 0, stream>>>(W_h, wz, h0, C, outputs, h_out);
}